// Round 18
// baseline (532.088 us; speedup 1.0000x reference)
//
#include <hip/hip_runtime.h>

#define B_ 8
#define T_ 2048
#define C_ 768
#define H_ 3072
#define BT_ (B_ * T_)
#define BC_ (B_ * C_)
#define WSEG 64
#define NWSEG 32
#define LSEG 64
#define NLSEG 32
#define LWARM 96

typedef unsigned short u16;
typedef short bf16x8 __attribute__((ext_vector_type(8)));
typedef float f32x4 __attribute__((ext_vector_type(4)));

__device__ __forceinline__ float b2f(u16 u) {
    union { unsigned i; float f; } w; w.i = ((unsigned)u) << 16; return w.f;
}
__device__ __forceinline__ u16 f2b(float f) {
    union { float f; unsigned i; } w; w.f = f;
    return (u16)((w.i + 0x7fffu + ((w.i >> 16) & 1u)) >> 16);
}

typedef __attribute__((address_space(3))) unsigned int lds_u32;
typedef const __attribute__((address_space(1))) unsigned int glb_u32;
__device__ __forceinline__ void gld_lds16(const void* g, void* l) {
    __builtin_amdgcn_global_load_lds((glb_u32*)g, (lds_u32*)l, 16, 0, 0);
}

// ------------------------------------------------ LayerNorm + token-shift mix, wave-per-row
template<int NOUT>
__global__ __launch_bounds__(512)
void lnmixw(const float* __restrict__ x, const float* __restrict__ w,
            const float* __restrict__ b,
            const float* __restrict__ m1, const float* __restrict__ m2,
            const float* __restrict__ m3,
            u16* __restrict__ o1, u16* __restrict__ o2, u16* __restrict__ o3) {
    const int wv = threadIdx.x >> 6, lane = threadIdx.x & 63;
    const int row = blockIdx.x * 8 + wv;
    const int t = row % T_;
    const float4* xr4 = (const float4*)(x + (size_t)row * C_);
    const float4* xp4 = (const float4*)(x + (size_t)(row - 1) * C_);
    float4 c[3], p[3];
#pragma unroll
    for (int j = 0; j < 3; ++j) c[j] = xr4[lane + j * 64];
    if (t > 0) {
#pragma unroll
        for (int j = 0; j < 3; ++j) p[j] = xp4[lane + j * 64];
    } else {
#pragma unroll
        for (int j = 0; j < 3; ++j) p[j] = make_float4(0.f, 0.f, 0.f, 0.f);
    }
    float s = 0.f, s2 = 0.f, ps = 0.f, ps2 = 0.f;
#pragma unroll
    for (int j = 0; j < 3; ++j) {
        s += c[j].x + c[j].y + c[j].z + c[j].w;
        s2 += c[j].x * c[j].x + c[j].y * c[j].y + c[j].z * c[j].z + c[j].w * c[j].w;
        ps += p[j].x + p[j].y + p[j].z + p[j].w;
        ps2 += p[j].x * p[j].x + p[j].y * p[j].y + p[j].z * p[j].z + p[j].w * p[j].w;
    }
#pragma unroll
    for (int off = 32; off > 0; off >>= 1) {
        s += __shfl_down(s, off);  s2 += __shfl_down(s2, off);
        ps += __shfl_down(ps, off); ps2 += __shfl_down(ps2, off);
    }
    s = __shfl(s, 0); s2 = __shfl(s2, 0); ps = __shfl(ps, 0); ps2 = __shfl(ps2, 0);
    const float mu = s * (1.f / C_);
    const float rs = rsqrtf(s2 * (1.f / C_) - mu * mu + 1e-5f);
    const float pmu = ps * (1.f / C_);
    const float prs = rsqrtf(ps2 * (1.f / C_) - pmu * pmu + 1e-5f);
    const size_t ob = (size_t)row * C_;
#pragma unroll
    for (int j = 0; j < 3; ++j) {
        int fi = lane + j * 64;
        float4 w4 = ((const float4*)w)[fi];
        float4 b4 = ((const float4*)b)[fi];
        float4 n, np;
        n.x = (c[j].x - mu) * rs * w4.x + b4.x;
        n.y = (c[j].y - mu) * rs * w4.y + b4.y;
        n.z = (c[j].z - mu) * rs * w4.z + b4.z;
        n.w = (c[j].w - mu) * rs * w4.w + b4.w;
        if (t > 0) {
            np.x = (p[j].x - pmu) * prs * w4.x + b4.x;
            np.y = (p[j].y - pmu) * prs * w4.y + b4.y;
            np.z = (p[j].z - pmu) * prs * w4.z + b4.z;
            np.w = (p[j].w - pmu) * prs * w4.w + b4.w;
        } else {
            np = make_float4(0.f, 0.f, 0.f, 0.f);
        }
        float4 mm = ((const float4*)m1)[fi];
        ushort4 ov;
        ov.x = f2b(fmaf(mm.x, n.x - np.x, np.x));
        ov.y = f2b(fmaf(mm.y, n.y - np.y, np.y));
        ov.z = f2b(fmaf(mm.z, n.z - np.z, np.z));
        ov.w = f2b(fmaf(mm.w, n.w - np.w, np.w));
        *(ushort4*)(o1 + ob + fi * 4) = ov;
        mm = ((const float4*)m2)[fi];
        ov.x = f2b(fmaf(mm.x, n.x - np.x, np.x));
        ov.y = f2b(fmaf(mm.y, n.y - np.y, np.y));
        ov.z = f2b(fmaf(mm.z, n.z - np.z, np.z));
        ov.w = f2b(fmaf(mm.w, n.w - np.w, np.w));
        *(ushort4*)(o2 + ob + fi * 4) = ov;
        if constexpr (NOUT == 3) {
            mm = ((const float4*)m3)[fi];
            ov.x = f2b(fmaf(mm.x, n.x - np.x, np.x));
            ov.y = f2b(fmaf(mm.y, n.y - np.y, np.y));
            ov.z = f2b(fmaf(mm.z, n.z - np.z, np.z));
            ov.w = f2b(fmaf(mm.w, n.w - np.w, np.w));
            *(ushort4*)(o3 + ob + fi * 4) = ov;
        }
    }
}

// ------------------------------------------------ batched transpose-cast f32[R][N] -> bf16[N][R]
struct TCJ { const float* s; u16* d; int R, Ncol, nbx, b0; };
struct TC7 { TCJ j[7]; };
__global__ void tcast_all(TC7 jobs) {
    __shared__ float t[32][33];
    int bid = blockIdx.x;
    int ji = 0;
#pragma unroll
    for (int k = 1; k < 7; ++k) if (bid >= jobs.j[k].b0) ji = k;
    TCJ jb = jobs.j[ji];
    int local = bid - jb.b0;
    int bx = local % jb.nbx, by = local / jb.nbx;
    int c0 = bx * 32, r0 = by * 32;
    int col = threadIdx.x & 31, rw = threadIdx.x >> 5;
#pragma unroll
    for (int i = 0; i < 4; ++i) {
        int r = rw + i * 8;
        t[r][col] = jb.s[(size_t)(r0 + r) * jb.Ncol + c0 + col];
    }
    __syncthreads();
#pragma unroll
    for (int i = 0; i < 4; ++i) {
        int r = rw + i * 8;
        jb.d[(size_t)(c0 + r) * jb.R + r0 + col] = f2b(t[col][r]);
    }
}

// ------------------------------------------------ 128x128 GEMM core (round-16 best): 4 waves,
// BK=64, double-buffered LDS = 64KB -> 2 blocks/CU. One barrier per K-tile.
__device__ __forceinline__ void gemm_core128(const u16* __restrict__ A,
                                             const u16* __restrict__ WT,
                                             int K, int m0, int n0,
                                             u16* L, f32x4 acc[4][4]) {
    const int tid = threadIdx.x;
    const int lane = tid & 63, wid = tid >> 6;
    const int wr = wid >> 1, wc = wid & 1;
    const int r16 = lane & 15, g = lane >> 4;

    const int srow = tid >> 3;                 // 0..31
    const int sunit = tid & 7;
    const int ssw = sunit ^ (srow & 7);
    const u16* gA = A + (size_t)(m0 + srow) * K + ssw * 8;
    const u16* gB = WT + (size_t)(n0 + srow) * K + ssw * 8;
    u16* lA = L + tid * 8;
    u16* lB = L + 8192 + tid * 8;

#define STGA(buf) do { \
        gld_lds16(gA,                  lA + (buf) * 16384); \
        gld_lds16(gA + (size_t)32 * K, lA + (buf) * 16384 + 2048); \
        gld_lds16(gA + (size_t)64 * K, lA + (buf) * 16384 + 4096); \
        gld_lds16(gA + (size_t)96 * K, lA + (buf) * 16384 + 6144); \
        gA += 64; } while (0)
#define STGB(buf) do { \
        gld_lds16(gB,                  lB + (buf) * 16384); \
        gld_lds16(gB + (size_t)32 * K, lB + (buf) * 16384 + 2048); \
        gld_lds16(gB + (size_t)64 * K, lB + (buf) * 16384 + 4096); \
        gld_lds16(gB + (size_t)96 * K, lB + (buf) * 16384 + 6144); \
        gB += 64; } while (0)

    int offA[4], offB[4];
#pragma unroll
    for (int m = 0; m < 4; ++m) {
        int row = wr * 64 + m * 16 + r16;
        offA[m] = row * 64 + (g ^ (row & 7)) * 8;
    }
#pragma unroll
    for (int n = 0; n < 4; ++n) {
        int rob = wc * 64 + n * 16 + r16;
        offB[n] = 8192 + rob * 64 + (g ^ (rob & 7)) * 8;
    }

    const int nt = K >> 6;
    STGA(0); STGB(0);
    asm volatile("s_waitcnt vmcnt(0)" ::: "memory");
    __builtin_amdgcn_sched_barrier(0);
    __builtin_amdgcn_s_barrier();

    for (int t = 0; t < nt; ++t) {
        const u16* Lb = L + (t & 1) * 16384;
        const bool stg = (t + 1 < nt);
        bf16x8 a0[4], b0[4];
#pragma unroll
        for (int m = 0; m < 4; ++m) a0[m] = *(const bf16x8*)(Lb + offA[m]);
#pragma unroll
        for (int n = 0; n < 4; ++n) b0[n] = *(const bf16x8*)(Lb + offB[n]);
        __builtin_amdgcn_sched_barrier(0);
        if (stg) { STGA((t + 1) & 1); STGB((t + 1) & 1); }
        asm volatile("s_waitcnt lgkmcnt(0)" ::: "memory");
        __builtin_amdgcn_sched_barrier(0);
        __builtin_amdgcn_s_setprio(1);
#pragma unroll
        for (int m = 0; m < 4; ++m)
#pragma unroll
            for (int n = 0; n < 4; ++n)
                acc[m][n] = __builtin_amdgcn_mfma_f32_16x16x32_bf16(a0[m], b0[n], acc[m][n], 0, 0, 0);
        __builtin_amdgcn_s_setprio(0);
        __builtin_amdgcn_sched_barrier(0);
        bf16x8 a1[4], b1[4];
#pragma unroll
        for (int m = 0; m < 4; ++m) a1[m] = *(const bf16x8*)(Lb + (offA[m] ^ 32));
#pragma unroll
        for (int n = 0; n < 4; ++n) b1[n] = *(const bf16x8*)(Lb + (offB[n] ^ 32));
        asm volatile("s_waitcnt lgkmcnt(0)" ::: "memory");
        __builtin_amdgcn_sched_barrier(0);
        __builtin_amdgcn_s_setprio(1);
#pragma unroll
        for (int m = 0; m < 4; ++m)
#pragma unroll
            for (int n = 0; n < 4; ++n)
                acc[m][n] = __builtin_amdgcn_mfma_f32_16x16x32_bf16(a1[m], b1[n], acc[m][n], 0, 0, 0);
        __builtin_amdgcn_s_setprio(0);
        __builtin_amdgcn_sched_barrier(0);
        if (stg) {
            asm volatile("s_waitcnt vmcnt(0)" ::: "memory");
            __builtin_amdgcn_sched_barrier(0);
            __builtin_amdgcn_s_barrier();
        }
    }
#undef STGA
#undef STGB
}

// bijective XCD-chunked remap (m204) + GROUP_M=4 super-tiling
__device__ __forceinline__ void xcd_remap2(int& bx, int& by) {
    const int gx = gridDim.x;
    const int nwg = gx * gridDim.y;
    const int lin = blockIdx.y * gx + blockIdx.x;
    const int q = nwg >> 3, r = nwg & 7;
    const int xcd = lin & 7, pos = lin >> 3;
    const int nid = (xcd < r ? xcd * (q + 1) : r * (q + 1) + (xcd - r) * q) + pos;
    const int g4 = gx << 2;
    const int grp = nid / g4, rem = nid - grp * g4;
    by = (grp << 2) + (rem & 3);
    bx = rem >> 2;
}

// Coalesced epilogue: per-wave LDS repack -> 16B full-line stores (kills L2 write-allocate).
// Lrep = the LDS dbuf half NOT read by the final K-tile (WAR-safe past the tile nt-2 barrier).
__device__ __forceinline__ void epilogue128(f32x4 acc[4][4], u16* O, const u16* Emul,
                                            int m0, int n0, int N, int mode, bool emul,
                                            u16* L, int K) {
    const int lane = threadIdx.x & 63, wid = threadIdx.x >> 6;
    const int wr = wid >> 1, wc = wid & 1;
    const int r16 = lane & 15, g = lane >> 4;
    u16* Wv = L + ((K >> 6) & 1) * 16384 + wid * 4096;   // 64x64 u16 per wave
#pragma unroll
    for (int m = 0; m < 4; ++m)
#pragma unroll
        for (int n = 0; n < 4; ++n)
#pragma unroll
            for (int j = 0; j < 4; ++j) {
                int lr = m * 16 + g * 4 + j;
                int lc = n * 16 + r16;
                float v = acc[m][n][j];
                if (mode == 1) v = 1.f / (1.f + expf(-v));
                else if (mode == 2) { v = fmaxf(v, 0.f); v = v * v; }
                if (emul) {
                    size_t o = (size_t)(m0 + wr * 64 + lr) * N + n0 + wc * 64 + lc;
                    v *= b2f(Emul[o]);
                }
                Wv[lr * 64 + lc] = f2b(v);
            }
    asm volatile("s_waitcnt lgkmcnt(0)" ::: "memory");
    __builtin_amdgcn_sched_barrier(0);
    const int rrow = lane >> 3, slot = lane & 7;
#pragma unroll
    for (int p = 0; p < 8; ++p) {
        int lr = p * 8 + rrow;
        bf16x8 vv = *(const bf16x8*)(Wv + lr * 64 + slot * 8);
        size_t o = (size_t)(m0 + wr * 64 + lr) * N + n0 + wc * 64 + slot * 8;
        *(bf16x8*)(O + o) = vv;
    }
}

// ------------------------------------------------ single GEMM (bf16 out), 128x128 tile
template<int MODE, bool EMUL>
__global__ __launch_bounds__(256, 2)
void gemm128(const u16* __restrict__ A, const u16* __restrict__ WT,
             u16* __restrict__ Cout, const u16* __restrict__ Emul, int N, int K) {
    __shared__ u16 L[32768];
    int bx, by;
    xcd_remap2(bx, by);
    const int m0 = by << 7, n0 = bx << 7;
    f32x4 acc[4][4];
#pragma unroll
    for (int i = 0; i < 4; ++i)
#pragma unroll
        for (int j = 0; j < 4; ++j)
#pragma unroll
            for (int q = 0; q < 4; ++q) acc[i][j][q] = 0.f;
    gemm_core128(A, WT, K, m0, n0, L, acc);
    epilogue128(acc, Cout, Emul, m0, n0, N, MODE, EMUL, L, K);
}

// ------------------------------------------------ fused K/V/R projections (blockIdx.z = slice)
struct P3 {
    const u16 *A0, *A1, *A2;
    const u16 *W0, *W1, *W2;
    u16 *O0, *O1, *O2;
};
__global__ __launch_bounds__(256, 2)
void proj3(P3 p, int N, int K) {
    __shared__ u16 L[32768];
    const int z = blockIdx.z;
    const u16* A = (z == 0) ? p.A0 : (z == 1) ? p.A1 : p.A2;
    const u16* W = (z == 0) ? p.W0 : (z == 1) ? p.W1 : p.W2;
    u16* O = (z == 0) ? p.O0 : (z == 1) ? p.O1 : p.O2;
    int bx, by;
    xcd_remap2(bx, by);
    const int m0 = by << 7, n0 = bx << 7;
    f32x4 acc[4][4];
#pragma unroll
    for (int i = 0; i < 4; ++i)
#pragma unroll
        for (int j = 0; j < 4; ++j)
#pragma unroll
            for (int q = 0; q < 4; ++q) acc[i][j][q] = 0.f;
    gemm_core128(A, W, K, m0, n0, L, acc);
    epilogue128(acc, O, nullptr, m0, n0, N, (z == 2) ? 1 : 0, false, L, K);
}

// ------------------------------------------------ fused FFN1 (relu^2) + Rr (sigmoid)
struct J2 {
    const u16 *A0, *W0; u16 *O0;   // FFN1: N=3072 (24 col-tiles)
    const u16 *A1, *W1; u16 *O1;   // Rr:   N=768  (6 col-tiles)
};
__global__ __launch_bounds__(256, 2)
void ffn1rr(J2 p, int K) {
    __shared__ u16 L[32768];
    int bx, by;
    xcd_remap2(bx, by);
    const bool isF = (bx < 24);
    const u16* A = isF ? p.A0 : p.A1;
    const u16* W = isF ? p.W0 : p.W1;
    u16* O = isF ? p.O0 : p.O1;
    const int N = isF ? 3072 : 768;
    const int m0 = by << 7;
    const int n0 = (isF ? bx : bx - 24) << 7;
    f32x4 acc[4][4];
#pragma unroll
    for (int i = 0; i < 4; ++i)
#pragma unroll
        for (int j = 0; j < 4; ++j)
#pragma unroll
            for (int q = 0; q < 4; ++q) acc[i][j][q] = 0.f;
    gemm_core128(A, W, K, m0, n0, L, acc);
    epilogue128(acc, O, nullptr, m0, n0, N, isF ? 2 : 1, false, L, K);
}

// ------------------------------------------------ WKV segmented scan, 2 channels/thread
__global__ void wkv_p1(const float* __restrict__ td, const u16* __restrict__ K,
                       const u16* __restrict__ V, float* __restrict__ st) {
    int idx = blockIdx.x * 256 + threadIdx.x;
    int seg = blockIdx.y;
    int c2 = idx * 2;
    int b = c2 / C_, c = c2 - b * C_;
    float w0 = -expf(td[c]), w1 = -expf(td[c + 1]);
    size_t off = (size_t)b * T_ * C_ + (size_t)seg * WSEG * C_ + c;
    float aa0 = 0.f, bb0 = 0.f, pp0 = -1e38f;
    float aa1 = 0.f, bb1 = 0.f, pp1 = -1e38f;
#pragma unroll 4
    for (int i = 0; i < WSEG; ++i) {
        ushort2 k2 = *(const ushort2*)(K + off + (size_t)i * C_);
        ushort2 v2 = *(const ushort2*)(V + off + (size_t)i * C_);
        {
            float kt = b2f(k2.x), vt = b2f(v2.x);
            float ww = pp0 + w0;
            float p = fmaxf(ww, kt);
            float e1 = expf(ww - p), e2 = expf(kt - p);
            aa0 = e1 * aa0 + e2 * vt; bb0 = e1 * bb0 + e2; pp0 = p;
        }
        {
            float kt = b2f(k2.y), vt = b2f(v2.y);
            float ww = pp1 + w1;
            float p = fmaxf(ww, kt);
            float e1 = expf(ww - p), e2 = expf(kt - p);
            aa1 = e1 * aa1 + e2 * vt; bb1 = e1 * bb1 + e2; pp1 = p;
        }
    }
    int sidx = seg * 3 * BC_ + b * C_ + c;
    *(float2*)(st + sidx) = make_float2(aa0, aa1);
    *(float2*)(st + sidx + BC_) = make_float2(bb0, bb1);
    *(float2*)(st + sidx + 2 * BC_) = make_float2(pp0, pp1);
}

__global__ void wkv_p3(const float* __restrict__ td, const float* __restrict__ tf,
                       const u16* __restrict__ K, const u16* __restrict__ V,
                       const u16* __restrict__ R, const float* __restrict__ st,
                       u16* __restrict__ RY) {
    int idx = blockIdx.x * 256 + threadIdx.x;
    int seg = blockIdx.y;
    int c2 = idx * 2;
    int b = c2 / C_, c = c2 - b * C_;
    float w0 = -expf(td[c]), w1 = -expf(td[c + 1]);
    float u0 = tf[c], u1 = tf[c + 1];
    float wL0 = w0 * (float)WSEG, wL1 = w1 * (float)WSEG;
    float aa0 = 0.f, bb0 = 0.f, pp0 = -1e38f;
    float aa1 = 0.f, bb1 = 0.f, pp1 = -1e38f;
    for (int s = 0; s < seg; ++s) {
        int sidx = s * 3 * BC_ + b * C_ + c;
        float2 la = *(const float2*)(st + sidx);
        float2 lb = *(const float2*)(st + sidx + BC_);
        float2 lp = *(const float2*)(st + sidx + 2 * BC_);
        {
            float ppw = pp0 + wL0;
            float p = fmaxf(ppw, lp.x);
            float e1 = expf(ppw - p), e2 = expf(lp.x - p);
            aa0 = e1 * aa0 + e2 * la.x; bb0 = e1 * bb0 + e2 * lb.x; pp0 = p;
        }
        {
            float ppw = pp1 + wL1;
            float p = fmaxf(ppw, lp.y);
            float e1 = expf(ppw - p), e2 = expf(lp.y - p);
            aa1 = e1 * aa1 + e2 * la.y; bb1 = e1 * bb1 + e2 * lb.y; pp1 = p;
        }
    }
    size_t off = (size_t)b * T_ * C_ + (size_t)seg * WSEG * C_ + c;
#pragma unroll 4
    for (int i = 0; i < WSEG; ++i) {
        ushort2 k2 = *(const ushort2*)(K + off + (size_t)i * C_);
        ushort2 v2 = *(const ushort2*)(V + off + (size_t)i * C_);
        ushort2 r2 = *(const ushort2*)(R + off + (size_t)i * C_);
        ushort2 o2v;
        {
            float kt = b2f(k2.x), vt = b2f(v2.x), rr = b2f(r2.x);
            float ww = u0 + kt;
            float p = fmaxf(pp0, ww);
            float e1 = expf(pp0 - p), e2 = expf(ww - p);
            o2v.x = f2b(rr * (e1 * aa0 + e2 * vt) / (e1 * bb0 + e2));
            float ww2 = pp0 + w0;
            float p2 = fmaxf(ww2, kt);
            float e1b = expf(ww2 - p2), e2b = expf(kt - p2);
            aa0 = e1b * aa0 + e2b * vt; bb0 = e1b * bb0 + e2b; pp0 = p2;
        }
        {
            float kt = b2f(k2.y), vt = b2f(v2.y), rr = b2f(r2.y);
            float ww = u1 + kt;
            float p = fmaxf(pp1, ww);
            float e1 = expf(pp1 - p), e2 = expf(ww - p);
            o2v.y = f2b(rr * (e1 * aa1 + e2 * vt) / (e1 * bb1 + e2));
            float ww2 = pp1 + w1;
            float p2 = fmaxf(ww2, kt);
            float e1b = expf(ww2 - p2), e2b = expf(kt - p2);
            aa1 = e1b * aa1 + e2b * vt; bb1 = e1b * bb1 + e2b; pp1 = p2;
        }
        *(ushort2*)(RY + off + (size_t)i * C_) = o2v;
    }
}

// ------------------------------------------------ LIF + residual, 2 channels/thread
__global__ void lif_add_b(const u16* __restrict__ cur, const float* __restrict__ base,
                          float* __restrict__ out) {
    int idx = blockIdx.x * 256 + threadIdx.x;
    int seg = blockIdx.y;
    int c2 = idx * 2;
    int b = c2 / C_, c = c2 - b * C_;
    size_t rowbase = (size_t)b * T_ * C_ + c;
    int t0 = seg * LSEG;
    int tw = t0 - LWARM; if (tw < 0) tw = 0;
    int nw = t0 - tw;
    float v0 = 0.f, v1 = 0.f;
    const u16* cp = cur + rowbase + (size_t)tw * C_;
#pragma unroll 8
    for (int i = 0; i < nw; ++i) {
        ushort2 x2 = *(const ushort2*)(cp + (size_t)i * C_);
        v0 += (b2f(x2.x) - v0) * 0.5f;
        v0 = (v0 >= 1.f) ? 0.f : v0;
        v1 += (b2f(x2.y) - v1) * 0.5f;
        v1 = (v1 >= 1.f) ? 0.f : v1;
    }
    const u16* cq = cur + rowbase + (size_t)t0 * C_;
    const float* bp = base + rowbase + (size_t)t0 * C_;
    float* op = out + rowbase + (size_t)t0 * C_;
#pragma unroll 8
    for (int i = 0; i < LSEG; ++i) {
        ushort2 x2 = *(const ushort2*)(cq + (size_t)i * C_);
        float2 b2 = *(const float2*)(bp + (size_t)i * C_);
        v0 += (b2f(x2.x) - v0) * 0.5f;
        float s0 = (v0 >= 1.f) ? 1.f : 0.f;
        v1 += (b2f(x2.y) - v1) * 0.5f;
        float s1 = (v1 >= 1.f) ? 1.f : 0.f;
        *(float2*)(op + (size_t)i * C_) = make_float2(b2.x + s0, b2.y + s1);
        v0 = (s0 > 0.f) ? 0.f : v0;
        v1 = (s1 > 0.f) ? 0.f : v1;
    }
}

// ------------------------------------------------ launcher
extern "C" void kernel_launch(void* const* d_in, const int* in_sizes, int n_in,
                              void* d_out, int out_size, void* d_ws, size_t ws_size,
                              hipStream_t stream) {
    const float* x    = (const float*)d_in[0];
    const float* ln1w = (const float*)d_in[1];
    const float* ln1b = (const float*)d_in[2];
    const float* ln2w = (const float*)d_in[3];
    const float* ln2b = (const float*)d_in[4];
    const float* td   = (const float*)d_in[5];
    const float* tf   = (const float*)d_in[6];
    const float* amk  = (const float*)d_in[7];
    const float* amv  = (const float*)d_in[8];
    const float* amr  = (const float*)d_in[9];
    const float* aWk  = (const float*)d_in[10];
    const float* aWv  = (const float*)d_in[11];
    const float* aWr  = (const float*)d_in[12];
    const float* aWo  = (const float*)d_in[13];
    const float* fmk  = (const float*)d_in[14];
    const float* fmr  = (const float*)d_in[15];
    const float* fWk  = (const float*)d_in[16];
    const float* fWv  = (const float*)d_in[17];
    const float* fWr  = (const float*)d_in[18];
    float* out = (float*)d_out;

    const size_t NBC = (size_t)BT_ * C_;
    u16* WkT = (u16*)d_ws;
    u16* WvT = WkT + 589824;
    u16* WrT = WvT + 589824;
    u16* WoT = WrT + 589824;
    u16* FrT = WoT + 589824;
    u16* FkT = FrT + 589824;                  // [3072][768]
    u16* FvT = FkT + 2359296;                 // [768][3072]
    float* st  = (float*)(FvT + 2359296);
    u16* S0 = (u16*)(st + NWSEG * 3 * BC_);
    u16* S1 = S0 + NBC;
    u16* S2 = S1 + NBC;
    u16* S3 = S2 + NBC;
    u16* Hbuf = S3 + NBC;
    size_t fixed_b = (size_t)((char*)Hbuf - (char*)d_ws);

    int NCH = 4;
    if (ws_size >= fixed_b + ((size_t)BT_ * H_ + NBC) * 2) NCH = 1;
    else if (ws_size >= fixed_b + ((size_t)(BT_ / 2) * H_ + NBC / 2) * 2) NCH = 2;
    const int CH = BT_ / NCH;
    u16* Fbuf = Hbuf + (size_t)CH * H_;

    u16* Kb = (u16*)d_out;
    u16* Vb = Kb + NBC;

    // 0. weights -> bf16 [N][K]
    {
        TC7 jobs;
        const float* srcs[7] = {aWk, aWv, aWr, aWo, fWr, fWk, fWv};
        u16* dsts[7] = {WkT, WvT, WrT, WoT, FrT, FkT, FvT};
        int Rs[7]    = {768, 768, 768, 768, 768, 768, 3072};
        int Ns[7]    = {768, 768, 768, 768, 768, 3072, 768};
        int b0 = 0;
        for (int k = 0; k < 7; ++k) {
            jobs.j[k].s = srcs[k]; jobs.j[k].d = dsts[k];
            jobs.j[k].R = Rs[k]; jobs.j[k].Ncol = Ns[k];
            jobs.j[k].nbx = Ns[k] / 32; jobs.j[k].b0 = b0;
            b0 += (Ns[k] / 32) * (Rs[k] / 32);
        }
        tcast_all<<<b0, 256, 0, stream>>>(jobs);
    }

    // 1. xk,xv,xr = mix(ln1(x)) -> S0,S1,S2
    lnmixw<3><<<BT_ / 8, 512, 0, stream>>>(x, ln1w, ln1b, amk, amv, amr, S0, S1, S2);
    // 2. K,V,sigmoid(R)
    {
        P3 p{S0, S1, S2, WkT, WvT, WrT, Kb, Vb, S3};
        proj3<<<dim3(6, 128, 3), 256, 0, stream>>>(p, C_, C_);
    }
    // 3. RY = sigmoid(R) * wkv(K,V) -> S0
    wkv_p1<<<dim3(BC_ / 512, NWSEG), 256, 0, stream>>>(td, Kb, Vb, st);
    wkv_p3<<<dim3(BC_ / 512, NWSEG), 256, 0, stream>>>(td, tf, Kb, Vb, S3, st, S0);
    // 4. A_out = RY @ Wo -> bf16 S1
    gemm128<0, false><<<dim3(6, 128), 256, 0, stream>>>(S0, WoT, S1, nullptr, C_, C_);
    // 5. X2 = x + lif(A_out) -> d_out
    lif_add_b<<<dim3(BC_ / 512, NLSEG), 256, 0, stream>>>(S1, x, out);
    // 6. xk2 -> S0, xr2 -> S1
    lnmixw<2><<<BT_ / 8, 512, 0, stream>>>(out, ln2w, ln2b, fmk, fmr, nullptr, S0, S1, nullptr);

    if (NCH == 1) {
        J2 p{S0, FkT, Hbuf, S1, FrT, S2};
        ffn1rr<<<dim3(30, 128), 256, 0, stream>>>(p, C_);
        gemm128<0, true><<<dim3(6, 128), 256, 0, stream>>>(Hbuf, FvT, Fbuf, S2, C_, H_);
        lif_add_b<<<dim3(BC_ / 512, NLSEG), 256, 0, stream>>>(Fbuf, out, out);
    } else {
        gemm128<1, false><<<dim3(6, 128), 256, 0, stream>>>(S1, FrT, S2, nullptr, C_, C_);
        for (int ch = 0; ch < NCH; ++ch) {
            const u16* xk2c = S0 + (size_t)ch * CH * C_;
            const u16* rrc  = S2 + (size_t)ch * CH * C_;
            gemm128<2, false><<<dim3(24, CH / 128), 256, 0, stream>>>(xk2c, FkT, Hbuf, nullptr, H_, C_);
            gemm128<0, true><<<dim3(6, CH / 128), 256, 0, stream>>>(Hbuf, FvT, Fbuf, rrc, C_, H_);
            lif_add_b<<<dim3((CH / T_) * C_ / 512, NLSEG), 256, 0, stream>>>(
                Fbuf, out + (size_t)ch * CH * C_, out + (size_t)ch * CH * C_);
        }
    }
}

// Round 19
// 524.390 us; speedup vs baseline: 1.0147x; 1.0147x over previous
//
#include <hip/hip_runtime.h>

#define B_ 8
#define T_ 2048
#define C_ 768
#define H_ 3072
#define BT_ (B_ * T_)
#define BC_ (B_ * C_)
#define WSEG 64
#define NWSEG 32
#define LSEG 64
#define NLSEG 32
#define LWARM 96

typedef unsigned short u16;
typedef short bf16x8 __attribute__((ext_vector_type(8)));
typedef float f32x4 __attribute__((ext_vector_type(4)));

__device__ __forceinline__ float b2f(u16 u) {
    union { unsigned i; float f; } w; w.i = ((unsigned)u) << 16; return w.f;
}
__device__ __forceinline__ u16 f2b(float f) {
    union { float f; unsigned i; } w; w.f = f;
    return (u16)((w.i + 0x7fffu + ((w.i >> 16) & 1u)) >> 16);
}

typedef __attribute__((address_space(3))) unsigned int lds_u32;
typedef const __attribute__((address_space(1))) unsigned int glb_u32;
__device__ __forceinline__ void gld_lds16(const void* g, void* l) {
    __builtin_amdgcn_global_load_lds((glb_u32*)g, (lds_u32*)l, 16, 0, 0);
}

// ------------------------------------------------ LayerNorm + token-shift mix, wave-per-row
template<int NOUT>
__global__ __launch_bounds__(512)
void lnmixw(const float* __restrict__ x, const float* __restrict__ w,
            const float* __restrict__ b,
            const float* __restrict__ m1, const float* __restrict__ m2,
            const float* __restrict__ m3,
            u16* __restrict__ o1, u16* __restrict__ o2, u16* __restrict__ o3) {
    const int wv = threadIdx.x >> 6, lane = threadIdx.x & 63;
    const int row = blockIdx.x * 8 + wv;
    const int t = row % T_;
    const float4* xr4 = (const float4*)(x + (size_t)row * C_);
    const float4* xp4 = (const float4*)(x + (size_t)(row - 1) * C_);
    float4 c[3], p[3];
#pragma unroll
    for (int j = 0; j < 3; ++j) c[j] = xr4[lane + j * 64];
    if (t > 0) {
#pragma unroll
        for (int j = 0; j < 3; ++j) p[j] = xp4[lane + j * 64];
    } else {
#pragma unroll
        for (int j = 0; j < 3; ++j) p[j] = make_float4(0.f, 0.f, 0.f, 0.f);
    }
    float s = 0.f, s2 = 0.f, ps = 0.f, ps2 = 0.f;
#pragma unroll
    for (int j = 0; j < 3; ++j) {
        s += c[j].x + c[j].y + c[j].z + c[j].w;
        s2 += c[j].x * c[j].x + c[j].y * c[j].y + c[j].z * c[j].z + c[j].w * c[j].w;
        ps += p[j].x + p[j].y + p[j].z + p[j].w;
        ps2 += p[j].x * p[j].x + p[j].y * p[j].y + p[j].z * p[j].z + p[j].w * p[j].w;
    }
#pragma unroll
    for (int off = 32; off > 0; off >>= 1) {
        s += __shfl_down(s, off);  s2 += __shfl_down(s2, off);
        ps += __shfl_down(ps, off); ps2 += __shfl_down(ps2, off);
    }
    s = __shfl(s, 0); s2 = __shfl(s2, 0); ps = __shfl(ps, 0); ps2 = __shfl(ps2, 0);
    const float mu = s * (1.f / C_);
    const float rs = rsqrtf(s2 * (1.f / C_) - mu * mu + 1e-5f);
    const float pmu = ps * (1.f / C_);
    const float prs = rsqrtf(ps2 * (1.f / C_) - pmu * pmu + 1e-5f);
    const size_t ob = (size_t)row * C_;
#pragma unroll
    for (int j = 0; j < 3; ++j) {
        int fi = lane + j * 64;
        float4 w4 = ((const float4*)w)[fi];
        float4 b4 = ((const float4*)b)[fi];
        float4 n, np;
        n.x = (c[j].x - mu) * rs * w4.x + b4.x;
        n.y = (c[j].y - mu) * rs * w4.y + b4.y;
        n.z = (c[j].z - mu) * rs * w4.z + b4.z;
        n.w = (c[j].w - mu) * rs * w4.w + b4.w;
        if (t > 0) {
            np.x = (p[j].x - pmu) * prs * w4.x + b4.x;
            np.y = (p[j].y - pmu) * prs * w4.y + b4.y;
            np.z = (p[j].z - pmu) * prs * w4.z + b4.z;
            np.w = (p[j].w - pmu) * prs * w4.w + b4.w;
        } else {
            np = make_float4(0.f, 0.f, 0.f, 0.f);
        }
        float4 mm = ((const float4*)m1)[fi];
        ushort4 ov;
        ov.x = f2b(fmaf(mm.x, n.x - np.x, np.x));
        ov.y = f2b(fmaf(mm.y, n.y - np.y, np.y));
        ov.z = f2b(fmaf(mm.z, n.z - np.z, np.z));
        ov.w = f2b(fmaf(mm.w, n.w - np.w, np.w));
        *(ushort4*)(o1 + ob + fi * 4) = ov;
        mm = ((const float4*)m2)[fi];
        ov.x = f2b(fmaf(mm.x, n.x - np.x, np.x));
        ov.y = f2b(fmaf(mm.y, n.y - np.y, np.y));
        ov.z = f2b(fmaf(mm.z, n.z - np.z, np.z));
        ov.w = f2b(fmaf(mm.w, n.w - np.w, np.w));
        *(ushort4*)(o2 + ob + fi * 4) = ov;
        if constexpr (NOUT == 3) {
            mm = ((const float4*)m3)[fi];
            ov.x = f2b(fmaf(mm.x, n.x - np.x, np.x));
            ov.y = f2b(fmaf(mm.y, n.y - np.y, np.y));
            ov.z = f2b(fmaf(mm.z, n.z - np.z, np.z));
            ov.w = f2b(fmaf(mm.w, n.w - np.w, np.w));
            *(ushort4*)(o3 + ob + fi * 4) = ov;
        }
    }
}

// ------------------------------------------------ batched transpose-cast f32[R][N] -> bf16[N][R]
struct TCJ { const float* s; u16* d; int R, Ncol, nbx, b0; };
struct TC7 { TCJ j[7]; };
__global__ void tcast_all(TC7 jobs) {
    __shared__ float t[32][33];
    int bid = blockIdx.x;
    int ji = 0;
#pragma unroll
    for (int k = 1; k < 7; ++k) if (bid >= jobs.j[k].b0) ji = k;
    TCJ jb = jobs.j[ji];
    int local = bid - jb.b0;
    int bx = local % jb.nbx, by = local / jb.nbx;
    int c0 = bx * 32, r0 = by * 32;
    int col = threadIdx.x & 31, rw = threadIdx.x >> 5;
#pragma unroll
    for (int i = 0; i < 4; ++i) {
        int r = rw + i * 8;
        t[r][col] = jb.s[(size_t)(r0 + r) * jb.Ncol + c0 + col];
    }
    __syncthreads();
#pragma unroll
    for (int i = 0; i < 4; ++i) {
        int r = rw + i * 8;
        jb.d[(size_t)(c0 + r) * jb.R + r0 + col] = f2b(t[col][r]);
    }
}

// ------------------------------------------------ 128x128 GEMM core (round-16 best): 4 waves,
// BK=64, double-buffered LDS = 64KB -> 2 blocks/CU. One barrier per K-tile.
__device__ __forceinline__ void gemm_core128(const u16* __restrict__ A,
                                             const u16* __restrict__ WT,
                                             int K, int m0, int n0,
                                             u16* L, f32x4 acc[4][4]) {
    const int tid = threadIdx.x;
    const int lane = tid & 63, wid = tid >> 6;
    const int wr = wid >> 1, wc = wid & 1;
    const int r16 = lane & 15, g = lane >> 4;

    const int srow = tid >> 3;                 // 0..31
    const int sunit = tid & 7;
    const int ssw = sunit ^ (srow & 7);
    const u16* gA = A + (size_t)(m0 + srow) * K + ssw * 8;
    const u16* gB = WT + (size_t)(n0 + srow) * K + ssw * 8;
    u16* lA = L + tid * 8;
    u16* lB = L + 8192 + tid * 8;

#define STGA(buf) do { \
        gld_lds16(gA,                  lA + (buf) * 16384); \
        gld_lds16(gA + (size_t)32 * K, lA + (buf) * 16384 + 2048); \
        gld_lds16(gA + (size_t)64 * K, lA + (buf) * 16384 + 4096); \
        gld_lds16(gA + (size_t)96 * K, lA + (buf) * 16384 + 6144); \
        gA += 64; } while (0)
#define STGB(buf) do { \
        gld_lds16(gB,                  lB + (buf) * 16384); \
        gld_lds16(gB + (size_t)32 * K, lB + (buf) * 16384 + 2048); \
        gld_lds16(gB + (size_t)64 * K, lB + (buf) * 16384 + 4096); \
        gld_lds16(gB + (size_t)96 * K, lB + (buf) * 16384 + 6144); \
        gB += 64; } while (0)

    int offA[4], offB[4];
#pragma unroll
    for (int m = 0; m < 4; ++m) {
        int row = wr * 64 + m * 16 + r16;
        offA[m] = row * 64 + (g ^ (row & 7)) * 8;
    }
#pragma unroll
    for (int n = 0; n < 4; ++n) {
        int rob = wc * 64 + n * 16 + r16;
        offB[n] = 8192 + rob * 64 + (g ^ (rob & 7)) * 8;
    }

    const int nt = K >> 6;
    STGA(0); STGB(0);
    asm volatile("s_waitcnt vmcnt(0)" ::: "memory");
    __builtin_amdgcn_sched_barrier(0);
    __builtin_amdgcn_s_barrier();

    for (int t = 0; t < nt; ++t) {
        const u16* Lb = L + (t & 1) * 16384;
        const bool stg = (t + 1 < nt);
        bf16x8 a0[4], b0[4];
#pragma unroll
        for (int m = 0; m < 4; ++m) a0[m] = *(const bf16x8*)(Lb + offA[m]);
#pragma unroll
        for (int n = 0; n < 4; ++n) b0[n] = *(const bf16x8*)(Lb + offB[n]);
        __builtin_amdgcn_sched_barrier(0);
        if (stg) { STGA((t + 1) & 1); STGB((t + 1) & 1); }
        asm volatile("s_waitcnt lgkmcnt(0)" ::: "memory");
        __builtin_amdgcn_sched_barrier(0);
        __builtin_amdgcn_s_setprio(1);
#pragma unroll
        for (int m = 0; m < 4; ++m)
#pragma unroll
            for (int n = 0; n < 4; ++n)
                acc[m][n] = __builtin_amdgcn_mfma_f32_16x16x32_bf16(a0[m], b0[n], acc[m][n], 0, 0, 0);
        __builtin_amdgcn_s_setprio(0);
        __builtin_amdgcn_sched_barrier(0);
        bf16x8 a1[4], b1[4];
#pragma unroll
        for (int m = 0; m < 4; ++m) a1[m] = *(const bf16x8*)(Lb + (offA[m] ^ 32));
#pragma unroll
        for (int n = 0; n < 4; ++n) b1[n] = *(const bf16x8*)(Lb + (offB[n] ^ 32));
        asm volatile("s_waitcnt lgkmcnt(0)" ::: "memory");
        __builtin_amdgcn_sched_barrier(0);
        __builtin_amdgcn_s_setprio(1);
#pragma unroll
        for (int m = 0; m < 4; ++m)
#pragma unroll
            for (int n = 0; n < 4; ++n)
                acc[m][n] = __builtin_amdgcn_mfma_f32_16x16x32_bf16(a1[m], b1[n], acc[m][n], 0, 0, 0);
        __builtin_amdgcn_s_setprio(0);
        __builtin_amdgcn_sched_barrier(0);
        if (stg) {
            asm volatile("s_waitcnt vmcnt(0)" ::: "memory");
            __builtin_amdgcn_sched_barrier(0);
            __builtin_amdgcn_s_barrier();
        }
    }
#undef STGA
#undef STGB
}

// bijective XCD-chunked remap (m204) + GROUP_M=4 super-tiling
__device__ __forceinline__ void xcd_remap2(int& bx, int& by) {
    const int gx = gridDim.x;
    const int nwg = gx * gridDim.y;
    const int lin = blockIdx.y * gx + blockIdx.x;
    const int q = nwg >> 3, r = nwg & 7;
    const int xcd = lin & 7, pos = lin >> 3;
    const int nid = (xcd < r ? xcd * (q + 1) : r * (q + 1) + (xcd - r) * q) + pos;
    const int g4 = gx << 2;
    const int grp = nid / g4, rem = nid - grp * g4;
    by = (grp << 2) + (rem & 3);
    bx = rem >> 2;
}

__device__ __forceinline__ void epilogue128(f32x4 acc[4][4], u16* O, const u16* Emul,
                                            int m0, int n0, int N, int mode, bool emul) {
    const int lane = threadIdx.x & 63, wid = threadIdx.x >> 6;
    const int wr = wid >> 1, wc = wid & 1;
    const int r16 = lane & 15, g = lane >> 4;
#pragma unroll
    for (int m = 0; m < 4; ++m)
#pragma unroll
        for (int n = 0; n < 4; ++n)
#pragma unroll
            for (int j = 0; j < 4; ++j) {
                int row = m0 + wr * 64 + m * 16 + g * 4 + j;
                int col = n0 + wc * 64 + n * 16 + r16;
                float v = acc[m][n][j];
                if (mode == 1) v = 1.f / (1.f + expf(-v));
                else if (mode == 2) { v = fmaxf(v, 0.f); v = v * v; }
                size_t o = (size_t)row * N + col;
                if (emul) v *= b2f(Emul[o]);
                O[o] = f2b(v);
            }
}

// ------------------------------------------------ single GEMM (bf16 out), 128x128 tile
template<int MODE, bool EMUL>
__global__ __launch_bounds__(256, 2)
void gemm128(const u16* __restrict__ A, const u16* __restrict__ WT,
             u16* __restrict__ Cout, const u16* __restrict__ Emul, int N, int K) {
    __shared__ u16 L[32768];
    int bx, by;
    xcd_remap2(bx, by);
    const int m0 = by << 7, n0 = bx << 7;
    f32x4 acc[4][4];
#pragma unroll
    for (int i = 0; i < 4; ++i)
#pragma unroll
        for (int j = 0; j < 4; ++j)
#pragma unroll
            for (int q = 0; q < 4; ++q) acc[i][j][q] = 0.f;
    gemm_core128(A, WT, K, m0, n0, L, acc);
    epilogue128(acc, Cout, Emul, m0, n0, N, MODE, EMUL);
}

// ------------------------------------------------ fused K/V/R projections (blockIdx.z = slice)
struct P3 {
    const u16 *A0, *A1, *A2;
    const u16 *W0, *W1, *W2;
    u16 *O0, *O1, *O2;
};
__global__ __launch_bounds__(256, 2)
void proj3(P3 p, int N, int K) {
    __shared__ u16 L[32768];
    const int z = blockIdx.z;
    const u16* A = (z == 0) ? p.A0 : (z == 1) ? p.A1 : p.A2;
    const u16* W = (z == 0) ? p.W0 : (z == 1) ? p.W1 : p.W2;
    u16* O = (z == 0) ? p.O0 : (z == 1) ? p.O1 : p.O2;
    int bx, by;
    xcd_remap2(bx, by);
    const int m0 = by << 7, n0 = bx << 7;
    f32x4 acc[4][4];
#pragma unroll
    for (int i = 0; i < 4; ++i)
#pragma unroll
        for (int j = 0; j < 4; ++j)
#pragma unroll
            for (int q = 0; q < 4; ++q) acc[i][j][q] = 0.f;
    gemm_core128(A, W, K, m0, n0, L, acc);
    epilogue128(acc, O, nullptr, m0, n0, N, (z == 2) ? 1 : 0, false);
}

// ------------------------------------------------ fused FFN1 (relu^2) + Rr (sigmoid)
struct J2 {
    const u16 *A0, *W0; u16 *O0;   // FFN1: N=3072 (24 col-tiles)
    const u16 *A1, *W1; u16 *O1;   // Rr:   N=768  (6 col-tiles)
};
__global__ __launch_bounds__(256, 2)
void ffn1rr(J2 p, int K) {
    __shared__ u16 L[32768];
    int bx, by;
    xcd_remap2(bx, by);
    const bool isF = (bx < 24);
    const u16* A = isF ? p.A0 : p.A1;
    const u16* W = isF ? p.W0 : p.W1;
    u16* O = isF ? p.O0 : p.O1;
    const int N = isF ? 3072 : 768;
    const int m0 = by << 7;
    const int n0 = (isF ? bx : bx - 24) << 7;
    f32x4 acc[4][4];
#pragma unroll
    for (int i = 0; i < 4; ++i)
#pragma unroll
        for (int j = 0; j < 4; ++j)
#pragma unroll
            for (int q = 0; q < 4; ++q) acc[i][j][q] = 0.f;
    gemm_core128(A, W, K, m0, n0, L, acc);
    epilogue128(acc, O, nullptr, m0, n0, N, isF ? 2 : 1, false);
}

// ------------------------------------------------ WKV segmented scan, 2 channels/thread
__global__ void wkv_p1(const float* __restrict__ td, const u16* __restrict__ K,
                       const u16* __restrict__ V, float* __restrict__ st) {
    int idx = blockIdx.x * 256 + threadIdx.x;
    int seg = blockIdx.y;
    int c2 = idx * 2;
    int b = c2 / C_, c = c2 - b * C_;
    float w0 = -expf(td[c]), w1 = -expf(td[c + 1]);
    size_t off = (size_t)b * T_ * C_ + (size_t)seg * WSEG * C_ + c;
    float aa0 = 0.f, bb0 = 0.f, pp0 = -1e38f;
    float aa1 = 0.f, bb1 = 0.f, pp1 = -1e38f;
#pragma unroll 4
    for (int i = 0; i < WSEG; ++i) {
        ushort2 k2 = *(const ushort2*)(K + off + (size_t)i * C_);
        ushort2 v2 = *(const ushort2*)(V + off + (size_t)i * C_);
        {
            float kt = b2f(k2.x), vt = b2f(v2.x);
            float ww = pp0 + w0;
            float p = fmaxf(ww, kt);
            float e1 = expf(ww - p), e2 = expf(kt - p);
            aa0 = e1 * aa0 + e2 * vt; bb0 = e1 * bb0 + e2; pp0 = p;
        }
        {
            float kt = b2f(k2.y), vt = b2f(v2.y);
            float ww = pp1 + w1;
            float p = fmaxf(ww, kt);
            float e1 = expf(ww - p), e2 = expf(kt - p);
            aa1 = e1 * aa1 + e2 * vt; bb1 = e1 * bb1 + e2; pp1 = p;
        }
    }
    int sidx = seg * 3 * BC_ + b * C_ + c;
    *(float2*)(st + sidx) = make_float2(aa0, aa1);
    *(float2*)(st + sidx + BC_) = make_float2(bb0, bb1);
    *(float2*)(st + sidx + 2 * BC_) = make_float2(pp0, pp1);
}

__global__ void wkv_p3(const float* __restrict__ td, const float* __restrict__ tf,
                       const u16* __restrict__ K, const u16* __restrict__ V,
                       const u16* __restrict__ R, const float* __restrict__ st,
                       u16* __restrict__ RY) {
    int idx = blockIdx.x * 256 + threadIdx.x;
    int seg = blockIdx.y;
    int c2 = idx * 2;
    int b = c2 / C_, c = c2 - b * C_;
    float w0 = -expf(td[c]), w1 = -expf(td[c + 1]);
    float u0 = tf[c], u1 = tf[c + 1];
    float wL0 = w0 * (float)WSEG, wL1 = w1 * (float)WSEG;
    float aa0 = 0.f, bb0 = 0.f, pp0 = -1e38f;
    float aa1 = 0.f, bb1 = 0.f, pp1 = -1e38f;
    for (int s = 0; s < seg; ++s) {
        int sidx = s * 3 * BC_ + b * C_ + c;
        float2 la = *(const float2*)(st + sidx);
        float2 lb = *(const float2*)(st + sidx + BC_);
        float2 lp = *(const float2*)(st + sidx + 2 * BC_);
        {
            float ppw = pp0 + wL0;
            float p = fmaxf(ppw, lp.x);
            float e1 = expf(ppw - p), e2 = expf(lp.x - p);
            aa0 = e1 * aa0 + e2 * la.x; bb0 = e1 * bb0 + e2 * lb.x; pp0 = p;
        }
        {
            float ppw = pp1 + wL1;
            float p = fmaxf(ppw, lp.y);
            float e1 = expf(ppw - p), e2 = expf(lp.y - p);
            aa1 = e1 * aa1 + e2 * la.y; bb1 = e1 * bb1 + e2 * lb.y; pp1 = p;
        }
    }
    size_t off = (size_t)b * T_ * C_ + (size_t)seg * WSEG * C_ + c;
#pragma unroll 4
    for (int i = 0; i < WSEG; ++i) {
        ushort2 k2 = *(const ushort2*)(K + off + (size_t)i * C_);
        ushort2 v2 = *(const ushort2*)(V + off + (size_t)i * C_);
        ushort2 r2 = *(const ushort2*)(R + off + (size_t)i * C_);
        ushort2 o2v;
        {
            float kt = b2f(k2.x), vt = b2f(v2.x), rr = b2f(r2.x);
            float ww = u0 + kt;
            float p = fmaxf(pp0, ww);
            float e1 = expf(pp0 - p), e2 = expf(ww - p);
            o2v.x = f2b(rr * (e1 * aa0 + e2 * vt) / (e1 * bb0 + e2));
            float ww2 = pp0 + w0;
            float p2 = fmaxf(ww2, kt);
            float e1b = expf(ww2 - p2), e2b = expf(kt - p2);
            aa0 = e1b * aa0 + e2b * vt; bb0 = e1b * bb0 + e2b; pp0 = p2;
        }
        {
            float kt = b2f(k2.y), vt = b2f(v2.y), rr = b2f(r2.y);
            float ww = u1 + kt;
            float p = fmaxf(pp1, ww);
            float e1 = expf(pp1 - p), e2 = expf(ww - p);
            o2v.y = f2b(rr * (e1 * aa1 + e2 * vt) / (e1 * bb1 + e2));
            float ww2 = pp1 + w1;
            float p2 = fmaxf(ww2, kt);
            float e1b = expf(ww2 - p2), e2b = expf(kt - p2);
            aa1 = e1b * aa1 + e2b * vt; bb1 = e1b * bb1 + e2b; pp1 = p2;
        }
        *(ushort2*)(RY + off + (size_t)i * C_) = o2v;
    }
}

// ------------------------------------------------ LIF + residual, 2 channels/thread
__global__ void lif_add_b(const u16* __restrict__ cur, const float* __restrict__ base,
                          float* __restrict__ out) {
    int idx = blockIdx.x * 256 + threadIdx.x;
    int seg = blockIdx.y;
    int c2 = idx * 2;
    int b = c2 / C_, c = c2 - b * C_;
    size_t rowbase = (size_t)b * T_ * C_ + c;
    int t0 = seg * LSEG;
    int tw = t0 - LWARM; if (tw < 0) tw = 0;
    int nw = t0 - tw;
    float v0 = 0.f, v1 = 0.f;
    const u16* cp = cur + rowbase + (size_t)tw * C_;
#pragma unroll 8
    for (int i = 0; i < nw; ++i) {
        ushort2 x2 = *(const ushort2*)(cp + (size_t)i * C_);
        v0 += (b2f(x2.x) - v0) * 0.5f;
        v0 = (v0 >= 1.f) ? 0.f : v0;
        v1 += (b2f(x2.y) - v1) * 0.5f;
        v1 = (v1 >= 1.f) ? 0.f : v1;
    }
    const u16* cq = cur + rowbase + (size_t)t0 * C_;
    const float* bp = base + rowbase + (size_t)t0 * C_;
    float* op = out + rowbase + (size_t)t0 * C_;
#pragma unroll 8
    for (int i = 0; i < LSEG; ++i) {
        ushort2 x2 = *(const ushort2*)(cq + (size_t)i * C_);
        float2 b2 = *(const float2*)(bp + (size_t)i * C_);
        v0 += (b2f(x2.x) - v0) * 0.5f;
        float s0 = (v0 >= 1.f) ? 1.f : 0.f;
        v1 += (b2f(x2.y) - v1) * 0.5f;
        float s1 = (v1 >= 1.f) ? 1.f : 0.f;
        *(float2*)(op + (size_t)i * C_) = make_float2(b2.x + s0, b2.y + s1);
        v0 = (s0 > 0.f) ? 0.f : v0;
        v1 = (s1 > 0.f) ? 0.f : v1;
    }
}

// ------------------------------------------------ launcher
extern "C" void kernel_launch(void* const* d_in, const int* in_sizes, int n_in,
                              void* d_out, int out_size, void* d_ws, size_t ws_size,
                              hipStream_t stream) {
    const float* x    = (const float*)d_in[0];
    const float* ln1w = (const float*)d_in[1];
    const float* ln1b = (const float*)d_in[2];
    const float* ln2w = (const float*)d_in[3];
    const float* ln2b = (const float*)d_in[4];
    const float* td   = (const float*)d_in[5];
    const float* tf   = (const float*)d_in[6];
    const float* amk  = (const float*)d_in[7];
    const float* amv  = (const float*)d_in[8];
    const float* amr  = (const float*)d_in[9];
    const float* aWk  = (const float*)d_in[10];
    const float* aWv  = (const float*)d_in[11];
    const float* aWr  = (const float*)d_in[12];
    const float* aWo  = (const float*)d_in[13];
    const float* fmk  = (const float*)d_in[14];
    const float* fmr  = (const float*)d_in[15];
    const float* fWk  = (const float*)d_in[16];
    const float* fWv  = (const float*)d_in[17];
    const float* fWr  = (const float*)d_in[18];
    float* out = (float*)d_out;

    const size_t NBC = (size_t)BT_ * C_;
    u16* WkT = (u16*)d_ws;
    u16* WvT = WkT + 589824;
    u16* WrT = WvT + 589824;
    u16* WoT = WrT + 589824;
    u16* FrT = WoT + 589824;
    u16* FkT = FrT + 589824;                  // [3072][768]
    u16* FvT = FkT + 2359296;                 // [768][3072]
    float* st  = (float*)(FvT + 2359296);
    u16* S0 = (u16*)(st + NWSEG * 3 * BC_);
    u16* S1 = S0 + NBC;
    u16* S2 = S1 + NBC;
    u16* S3 = S2 + NBC;
    u16* Hbuf = S3 + NBC;
    size_t fixed_b = (size_t)((char*)Hbuf - (char*)d_ws);

    int NCH = 4;
    if (ws_size >= fixed_b + ((size_t)BT_ * H_ + NBC) * 2) NCH = 1;
    else if (ws_size >= fixed_b + ((size_t)(BT_ / 2) * H_ + NBC / 2) * 2) NCH = 2;
    const int CH = BT_ / NCH;
    u16* Fbuf = Hbuf + (size_t)CH * H_;

    u16* Kb = (u16*)d_out;
    u16* Vb = Kb + NBC;

    // 0. weights -> bf16 [N][K]
    {
        TC7 jobs;
        const float* srcs[7] = {aWk, aWv, aWr, aWo, fWr, fWk, fWv};
        u16* dsts[7] = {WkT, WvT, WrT, WoT, FrT, FkT, FvT};
        int Rs[7]    = {768, 768, 768, 768, 768, 768, 3072};
        int Ns[7]    = {768, 768, 768, 768, 768, 3072, 768};
        int b0 = 0;
        for (int k = 0; k < 7; ++k) {
            jobs.j[k].s = srcs[k]; jobs.j[k].d = dsts[k];
            jobs.j[k].R = Rs[k]; jobs.j[k].Ncol = Ns[k];
            jobs.j[k].nbx = Ns[k] / 32; jobs.j[k].b0 = b0;
            b0 += (Ns[k] / 32) * (Rs[k] / 32);
        }
        tcast_all<<<b0, 256, 0, stream>>>(jobs);
    }

    // 1. xk,xv,xr = mix(ln1(x)) -> S0,S1,S2
    lnmixw<3><<<BT_ / 8, 512, 0, stream>>>(x, ln1w, ln1b, amk, amv, amr, S0, S1, S2);
    // 2. K,V,sigmoid(R)
    {
        P3 p{S0, S1, S2, WkT, WvT, WrT, Kb, Vb, S3};
        proj3<<<dim3(6, 128, 3), 256, 0, stream>>>(p, C_, C_);
    }
    // 3. RY = sigmoid(R) * wkv(K,V) -> S0
    wkv_p1<<<dim3(BC_ / 512, NWSEG), 256, 0, stream>>>(td, Kb, Vb, st);
    wkv_p3<<<dim3(BC_ / 512, NWSEG), 256, 0, stream>>>(td, tf, Kb, Vb, S3, st, S0);
    // 4. A_out = RY @ Wo -> bf16 S1
    gemm128<0, false><<<dim3(6, 128), 256, 0, stream>>>(S0, WoT, S1, nullptr, C_, C_);
    // 5. X2 = x + lif(A_out) -> d_out
    lif_add_b<<<dim3(BC_ / 512, NLSEG), 256, 0, stream>>>(S1, x, out);
    // 6. xk2 -> S0, xr2 -> S1
    lnmixw<2><<<BT_ / 8, 512, 0, stream>>>(out, ln2w, ln2b, fmk, fmr, nullptr, S0, S1, nullptr);

    if (NCH == 1) {
        J2 p{S0, FkT, Hbuf, S1, FrT, S2};
        ffn1rr<<<dim3(30, 128), 256, 0, stream>>>(p, C_);
        gemm128<0, true><<<dim3(6, 128), 256, 0, stream>>>(Hbuf, FvT, Fbuf, S2, C_, H_);
        lif_add_b<<<dim3(BC_ / 512, NLSEG), 256, 0, stream>>>(Fbuf, out, out);
    } else {
        gemm128<1, false><<<dim3(6, 128), 256, 0, stream>>>(S1, FrT, S2, nullptr, C_, C_);
        for (int ch = 0; ch < NCH; ++ch) {
            const u16* xk2c = S0 + (size_t)ch * CH * C_;
            const u16* rrc  = S2 + (size_t)ch * CH * C_;
            gemm128<2, false><<<dim3(24, CH / 128), 256, 0, stream>>>(xk2c, FkT, Hbuf, nullptr, H_, C_);
            gemm128<0, true><<<dim3(6, CH / 128), 256, 0, stream>>>(Hbuf, FvT, Fbuf, rrc, C_, H_);
            lif_add_b<<<dim3((CH / T_) * C_ / 512, NLSEG), 256, 0, stream>>>(
                Fbuf, out + (size_t)ch * CH * C_, out + (size_t)ch * CH * C_);
        }
    }
}